// Round 1
// baseline (492.021 us; speedup 1.0000x reference)
//
#include <hip/hip_runtime.h>
#include <math.h>

#define BB 32
#define HH 16
#define DD 128
#define BSZ 16
#define MAXBLK 64
#define NCHUNK 4      // chunks per (b,h); 4 * 256 = 1024 = max context
#define CT 256        // tokens per chunk
#define CBLK 16       // paged blocks per chunk
#define SCALE 0.08838834764831845f

// Flash-decode chunk kernel: one workgroup (4 waves) per (b, h, chunk).
// Computes unnormalized partial output o_c, local max m_c, local exp-sum l_c.
// The new token (position len-1) is folded in from new_k/new_v inline —
// the paged caches are never mutated.
//
// R1 change vs baseline: all K/V cache traffic is float4 (16 B/lane,
// global_load_dwordx4) instead of float2. Lane mappings re-derived:
//   K block (pb,h) = 2048 contiguous floats laid out [d_hi=16][tok=16][x=8].
//     float4 wave covers 256 floats; lane l owns tok=(l>>1)&15, x=4*(l&1)+j,
//     d_hi = 2*ch + (l>>5), ch=0..7  -> 8 loads/lane/block (was 16).
//     Score reduce: shfl_xor(1) + shfl_xor(32).
//   V block = [tok=16][d=128]. float4 wave covers 2 tokens; lane l owns
//     tok = 2*t2 + (l>>5), dims 4*(l&31)+j  -> 8 loads/lane/block (was 16).
//     Halves merged with one shfl_xor(32) pass at the end.
__global__ __launch_bounds__(256) void attn_chunk_kernel(
    const float* __restrict__ q, const float* __restrict__ newk,
    const float* __restrict__ newv, const float* __restrict__ kc,
    const float* __restrict__ vc, const int* __restrict__ block_tables,
    const int* __restrict__ context_lens,
    float* __restrict__ o_part, float* __restrict__ m_part,
    float* __restrict__ l_part)
{
    __shared__ __align__(16) float s_scores[CT];
    __shared__ __align__(16) float s_q[DD];
    __shared__ float s_red[8];
    __shared__ __align__(16) float s_out[4][DD];

    int gid  = blockIdx.x;         // bh * NCHUNK + c
    int c    = gid & (NCHUNK - 1);
    int bh   = gid >> 2;
    int b    = bh >> 4;
    int h    = bh & 15;
    int tid  = threadIdx.x;
    int wave = tid >> 6;
    int lane = tid & 63;

    int len    = context_lens[b];
    int cstart = c * CT;
    if (cstart >= len) return;     // chunk entirely beyond context

    int nblk   = (len + 15) >> 4;
    int cb0    = c * CBLK;
    int cb_end = min(nblk, cb0 + CBLK);
    int last   = len - 1;
    bool haslast = (last >> 8) == c;   // this chunk holds the new token

    if (tid < DD) s_q[tid] = q[(size_t)bh * DD + tid] * SCALE;
    __syncthreads();

    int hi = lane >> 5;            // which half-wave (0/1)
    int xq = lane & 1;             // x-quad within token row (phase 1)
    int tk = (lane >> 1) & 15;     // token within paged block (phase 1)

    // q fragments this lane needs: d_hi = 2*ch + hi, x base = 4*xq.
    float4 rq[8];
#pragma unroll
    for (int ch = 0; ch < 8; ++ch)
        rq[ch] = *(const float4*)&s_q[(2 * ch + hi) * 8 + 4 * xq];

    const int* bt = block_tables + b * MAXBLK;

    // ---- Phase 1: scores. 8 x float4 per lane per paged block.
    for (int cb = cb0 + wave; cb < cb_end; cb += 4) {
        int pb = bt[cb];
        const float* kbase = kc + ((size_t)pb * HH + h) * 2048 + 4 * lane;
        float acc = 0.f;
#pragma unroll
        for (int ch = 0; ch < 8; ++ch) {
            float4 kv = *(const float4*)(kbase + ch * 256);
            acc += rq[ch].x * kv.x + rq[ch].y * kv.y
                 + rq[ch].z * kv.z + rq[ch].w * kv.w;
        }
        acc += __shfl_xor(acc, 1);    // merge x-quads
        acc += __shfl_xor(acc, 32);   // merge d_hi halves
        if (lane < 32 && (lane & 1) == 0) {
            int p = cb * 16 + tk;
            s_scores[(cb - cb0) * 16 + tk] = (p < len) ? acc : -INFINITY;
        }
    }
    __syncthreads();

    // ---- New-token score fix: recompute score at `last` from new_k.
    if (haslast && wave == 0) {
        float2 nk = *(const float2*)&newk[(size_t)bh * DD + 2 * lane];
        float part = s_q[2 * lane] * nk.x + s_q[2 * lane + 1] * nk.y;
#pragma unroll
        for (int off = 32; off; off >>= 1) part += __shfl_xor(part, off);
        if (lane == 0) s_scores[last - cstart] = part;
    }
    __syncthreads();

    // ---- Phase 2: local softmax over padded = (cb_end-cb0)*16 entries.
    int padded = (cb_end - cb0) * 16;
    float mloc = (tid < padded) ? s_scores[tid] : -INFINITY;
#pragma unroll
    for (int off = 32; off; off >>= 1) mloc = fmaxf(mloc, __shfl_xor(mloc, off));
    if (lane == 0) s_red[wave] = mloc;
    __syncthreads();
    float m = fmaxf(fmaxf(s_red[0], s_red[1]), fmaxf(s_red[2], s_red[3]));

    float e = 0.f;
    if (tid < padded) {
        e = __expf(s_scores[tid] - m);
        s_scores[tid] = e;              // unnormalized weights
    }
    float ssum = e;
#pragma unroll
    for (int off = 32; off; off >>= 1) ssum += __shfl_xor(ssum, off);
    if (lane == 0) s_red[4 + wave] = ssum;
    __syncthreads();
    float lsum = s_red[4] + s_red[5] + s_red[6] + s_red[7];

    // ---- Phase 3: o_c = sum_p e[p] * V[p,:]. 8 x float4 per lane per block.
    int dv = 4 * (lane & 31);          // output dims this lane owns
    float4 nv4 = make_float4(0.f, 0.f, 0.f, 0.f);
    if (haslast) nv4 = *(const float4*)&newv[(size_t)bh * DD + dv];
    int lastTok = haslast ? last : -1; // global token id of the new token

    float4 acc4 = make_float4(0.f, 0.f, 0.f, 0.f);
    for (int cb = cb0 + wave; cb < cb_end; cb += 4) {
        int pb = bt[cb];
        const float* vbase = vc + ((size_t)pb * HH + h) * 2048 + 4 * lane;
        int base_s = (cb - cb0) * 16 + hi;
        int base_p = cb * 16 + hi;
#pragma unroll
        for (int t2 = 0; t2 < 8; ++t2) {
            float w = s_scores[base_s + 2 * t2];        // LDS broadcast
            float4 vv = *(const float4*)(vbase + t2 * 256);
            if (base_p + 2 * t2 == lastTok) vv = nv4;   // new-token V
            acc4.x += w * vv.x;
            acc4.y += w * vv.y;
            acc4.z += w * vv.z;
            acc4.w += w * vv.w;
        }
    }
    // merge even/odd-token halves
    acc4.x += __shfl_xor(acc4.x, 32);
    acc4.y += __shfl_xor(acc4.y, 32);
    acc4.z += __shfl_xor(acc4.z, 32);
    acc4.w += __shfl_xor(acc4.w, 32);
    if (lane < 32) *(float4*)&s_out[wave][dv] = acc4;
    __syncthreads();

    if (tid < DD) {
        float o = s_out[0][tid] + s_out[1][tid] + s_out[2][tid] + s_out[3][tid];
        o_part[(size_t)gid * DD + tid] = o;
    }
    if (tid == 0) {
        m_part[gid] = m;
        l_part[gid] = lsum;
    }
}

// Log-sum-exp merge of the per-chunk partials. One block (2 waves) per (b,h).
__global__ __launch_bounds__(128) void attn_combine_kernel(
    const float* __restrict__ o_part, const float* __restrict__ m_part,
    const float* __restrict__ l_part, const int* __restrict__ context_lens,
    float* __restrict__ out)
{
    int bh  = blockIdx.x;
    int b   = bh >> 4;
    int tid = threadIdx.x;
    int len = context_lens[b];
    int nc  = (len + CT - 1) >> 8;

    float mi[NCHUNK];
    float m_g = -INFINITY;
    for (int i = 0; i < nc; ++i) {
        mi[i] = m_part[bh * NCHUNK + i];
        m_g = fmaxf(m_g, mi[i]);
    }
    float acc = 0.f, lg = 0.f;
    for (int i = 0; i < nc; ++i) {
        float w = __expf(mi[i] - m_g);
        lg  += w * l_part[bh * NCHUNK + i];
        acc += w * o_part[(size_t)(bh * NCHUNK + i) * DD + tid];
    }
    out[(size_t)bh * DD + tid] = acc / lg;
}

extern "C" void kernel_launch(void* const* d_in, const int* in_sizes, int n_in,
                              void* d_out, int out_size, void* d_ws, size_t ws_size,
                              hipStream_t stream) {
    const float* query        = (const float*)d_in[0];
    const float* key          = (const float*)d_in[1];
    const float* value        = (const float*)d_in[2];
    const float* key_cache    = (const float*)d_in[3];
    const float* value_cache  = (const float*)d_in[4];
    const int*   block_tables = (const int*)d_in[5];
    const int*   context_lens = (const int*)d_in[6];
    float*       out          = (float*)d_out;

    // Workspace layout: o_part [B*H*NCHUNK, 128] | m_part | l_part
    float* o_part = (float*)d_ws;
    float* m_part = o_part + (size_t)BB * HH * NCHUNK * DD;
    float* l_part = m_part + (size_t)BB * HH * NCHUNK;

    attn_chunk_kernel<<<BB * HH * NCHUNK, 256, 0, stream>>>(
        query, key, value, key_cache, value_cache, block_tables,
        context_lens, o_part, m_part, l_part);
    attn_combine_kernel<<<BB * HH, 128, 0, stream>>>(
        o_part, m_part, l_part, context_lens, out);
}

// Round 4
// 485.366 us; speedup vs baseline: 1.0137x; 1.0137x over previous
//
#include <hip/hip_runtime.h>
#include <math.h>

#define BB 32
#define HH 16
#define DD 128
#define MAXBLK 64
#define NCHUNK 4      // chunks per (b,h); 4 * 256 = 1024 = max context
#define CT 256        // tokens per chunk
#define CBLK 16       // paged blocks per chunk
#define SCALE 0.08838834764831845f

// R2 (2nd resubmit — rounds 2 and 3 both hit GPU acquisition timeouts,
// the kernel has never run): per-wave ONLINE-softmax flash-decode.
// Each wave owns a strided subset of the chunk's paged blocks and keeps
// running (m, l, o) entirely in registers — K and V loads of the same
// block are issued back-to-back (16 x float4 in flight per wave), there
// are NO barriers in the main loop, and the s_scores LDS round-trip is
// gone. One LSE merge across the 4 waves at the end. Combine unchanged.
//
// Layouts (per paged block pb, head h — 2048 contiguous floats each):
//   K: [d_hi=16][tok=16][x=8]. float4 lane map: tok=(l>>1)&15, x=4*(l&1),
//      d_hi=2*ch+(l>>5). Score reduce: shfl_xor(1) + shfl_xor(32).
//   V: [tok=16][d=128]. float4 lane map: tok=2*t2+(l>>5), d=4*(l&31).
//      Halves merged once at the end with shfl_xor(32).
__global__ __launch_bounds__(256) void attn_chunk_kernel(
    const float* __restrict__ q, const float* __restrict__ newk,
    const float* __restrict__ newv, const float* __restrict__ kc,
    const float* __restrict__ vc, const int* __restrict__ block_tables,
    const int* __restrict__ context_lens,
    float* __restrict__ o_part, float* __restrict__ m_part,
    float* __restrict__ l_part)
{
    __shared__ __align__(16) float s_q[DD];
    __shared__ __align__(16) float s_o[4][DD];
    __shared__ float s_m[4];
    __shared__ float s_l[4];

    int gid  = blockIdx.x;         // bh * NCHUNK + c
    int c    = gid & (NCHUNK - 1);
    int bh   = gid >> 2;
    int b    = bh >> 4;
    int h    = bh & 15;
    int tid  = threadIdx.x;
    int wave = tid >> 6;
    int lane = tid & 63;

    int len    = context_lens[b];
    int cstart = c * CT;
    if (cstart >= len) return;     // chunk entirely beyond context (uniform)

    int nblk   = (len + 15) >> 4;
    int cb0    = c * CBLK;
    int cb_end = min(nblk, cb0 + CBLK);
    int last   = len - 1;
    bool haslast = (last >> 8) == c;   // this chunk holds the new token

    if (tid < DD) s_q[tid] = q[(size_t)bh * DD + tid] * SCALE;
    __syncthreads();

    int hi = lane >> 5;            // half-wave
    int xq = lane & 1;             // x-quad (K map)
    int tk = (lane >> 1) & 15;     // token this lane scores (K map)
    int dv = 4 * (lane & 31);      // output dims this lane owns (V map)

    // q fragments: d_hi = 2*ch + hi, x base = 4*xq.
    float4 rq[8];
#pragma unroll
    for (int ch = 0; ch < 8; ++ch)
        rq[ch] = *(const float4*)&s_q[(2 * ch + hi) * 8 + 4 * xq];

    // New-token score (q.new_k, already scaled) + new-token V fragment.
    float s_last = 0.f;
    float4 nv4 = make_float4(0.f, 0.f, 0.f, 0.f);
    if (haslast) {
        float2 nk = *(const float2*)&newk[(size_t)bh * DD + 2 * lane];
        float part = s_q[2 * lane] * nk.x + s_q[2 * lane + 1] * nk.y;
#pragma unroll
        for (int off = 32; off; off >>= 1) part += __shfl_xor(part, off);
        s_last = part;
        nv4 = *(const float4*)&newv[(size_t)bh * DD + dv];
    }
    int lastTok = haslast ? last : -1;

    const int* bt = block_tables + b * MAXBLK;

    float  m_run = -INFINITY;
    float  l_run = 0.f;
    float4 acc4  = make_float4(0.f, 0.f, 0.f, 0.f);

#pragma unroll 1
    for (int cb = cb0 + wave; cb < cb_end; cb += 4) {
        int pb = bt[cb];
        const float* kbase = kc + ((size_t)pb * HH + h) * 2048 + 4 * lane;
        const float* vbase = vc + ((size_t)pb * HH + h) * 2048 + 4 * lane;

        // Issue K and V together: 16 x dwordx4 in flight per wave.
        float4 kf[8], vf[8];
#pragma unroll
        for (int i = 0; i < 8; ++i) kf[i] = *(const float4*)(kbase + i * 256);
#pragma unroll
        for (int i = 0; i < 8; ++i) vf[i] = *(const float4*)(vbase + i * 256);

        // Score for token tk of this block.
        float sc = 0.f;
#pragma unroll
        for (int i = 0; i < 8; ++i)
            sc += rq[i].x * kf[i].x + rq[i].y * kf[i].y
                + rq[i].z * kf[i].z + rq[i].w * kf[i].w;
        sc += __shfl_xor(sc, 1);    // merge x-quads
        sc += __shfl_xor(sc, 32);   // merge d_hi halves
        int p = cb * 16 + tk;
        if (p == lastTok) sc = s_last;    // new token overrides stale cache
        if (p >= len)     sc = -INFINITY; // mask padding

        // Block max over the 16 tokens (values duplicated in bits 0 and 5).
        float bm = sc;
        bm = fmaxf(bm, __shfl_xor(bm, 2));
        bm = fmaxf(bm, __shfl_xor(bm, 4));
        bm = fmaxf(bm, __shfl_xor(bm, 8));
        bm = fmaxf(bm, __shfl_xor(bm, 16));

        float mnew  = fmaxf(m_run, bm);          // finite: every cb has a valid token
        float scale = __expf(m_run - mnew);      // expf(-inf)=0 on first block
        acc4.x *= scale; acc4.y *= scale; acc4.z *= scale; acc4.w *= scale;

        // Weights for this lane's token parity + V accumulate.
        float lsum8 = 0.f;
#pragma unroll
        for (int t2 = 0; t2 < 8; ++t2) {
            int tt = 2 * t2 + hi;                        // token in block
            float st  = __shfl(sc, 4 * t2 + 2 * hi);     // lane 2*tt holds sc[tt]
            float wgt = __expf(st - mnew);               // 0 for masked tokens
            lsum8 += wgt;
            float4 vv = vf[t2];
            if (cb * 16 + tt == lastTok) vv = nv4;       // new-token V
            acc4.x += wgt * vv.x;
            acc4.y += wgt * vv.y;
            acc4.z += wgt * vv.z;
            acc4.w += wgt * vv.w;
        }
        l_run = l_run * scale + lsum8 + __shfl_xor(lsum8, 32);
        m_run = mnew;
    }

    // Merge even/odd-token halves (same m across the wave).
    acc4.x += __shfl_xor(acc4.x, 32);
    acc4.y += __shfl_xor(acc4.y, 32);
    acc4.z += __shfl_xor(acc4.z, 32);
    acc4.w += __shfl_xor(acc4.w, 32);
    if (lane < 32) *(float4*)&s_o[wave][dv] = acc4;
    if (lane == 0) { s_m[wave] = m_run; s_l[wave] = l_run; }
    __syncthreads();

    // Cross-wave LSE merge (waves with no blocks have m=-inf, l=0, o=0).
    if (tid < DD) {
        float mg = fmaxf(fmaxf(s_m[0], s_m[1]), fmaxf(s_m[2], s_m[3]));
        float w0 = __expf(s_m[0] - mg), w1 = __expf(s_m[1] - mg);
        float w2 = __expf(s_m[2] - mg), w3 = __expf(s_m[3] - mg);
        float o = w0 * s_o[0][tid] + w1 * s_o[1][tid]
                + w2 * s_o[2][tid] + w3 * s_o[3][tid];
        o_part[(size_t)gid * DD + tid] = o;
        if (tid == 0) {
            m_part[gid] = mg;
            l_part[gid] = w0 * s_l[0] + w1 * s_l[1] + w2 * s_l[2] + w3 * s_l[3];
        }
    }
}

// Log-sum-exp merge of the per-chunk partials. One block (2 waves) per (b,h).
__global__ __launch_bounds__(128) void attn_combine_kernel(
    const float* __restrict__ o_part, const float* __restrict__ m_part,
    const float* __restrict__ l_part, const int* __restrict__ context_lens,
    float* __restrict__ out)
{
    int bh  = blockIdx.x;
    int b   = bh >> 4;
    int tid = threadIdx.x;
    int len = context_lens[b];
    int nc  = (len + CT - 1) >> 8;

    float mi[NCHUNK];
    float m_g = -INFINITY;
    for (int i = 0; i < nc; ++i) {
        mi[i] = m_part[bh * NCHUNK + i];
        m_g = fmaxf(m_g, mi[i]);
    }
    float acc = 0.f, lg = 0.f;
    for (int i = 0; i < nc; ++i) {
        float w = __expf(mi[i] - m_g);
        lg  += w * l_part[bh * NCHUNK + i];
        acc += w * o_part[(size_t)(bh * NCHUNK + i) * DD + tid];
    }
    out[(size_t)bh * DD + tid] = acc / lg;
}

extern "C" void kernel_launch(void* const* d_in, const int* in_sizes, int n_in,
                              void* d_out, int out_size, void* d_ws, size_t ws_size,
                              hipStream_t stream) {
    const float* query        = (const float*)d_in[0];
    const float* key          = (const float*)d_in[1];
    const float* value        = (const float*)d_in[2];
    const float* key_cache    = (const float*)d_in[3];
    const float* value_cache  = (const float*)d_in[4];
    const int*   block_tables = (const int*)d_in[5];
    const int*   context_lens = (const int*)d_in[6];
    float*       out          = (float*)d_out;

    // Workspace layout: o_part [B*H*NCHUNK, 128] | m_part | l_part
    float* o_part = (float*)d_ws;
    float* m_part = o_part + (size_t)BB * HH * NCHUNK * DD;
    float* l_part = m_part + (size_t)BB * HH * NCHUNK;

    attn_chunk_kernel<<<BB * HH * NCHUNK, 256, 0, stream>>>(
        query, key, value, key_cache, value_cache, block_tables,
        context_lens, o_part, m_part, l_part);
    attn_combine_kernel<<<BB * HH, 128, 0, stream>>>(
        o_part, m_part, l_part, context_lens, out);
}